// Round 13
// baseline (110.688 us; speedup 1.0000x reference)
//
#include <hip/hip_runtime.h>
#include <math.h>

#define N_NODES 50000
#define N_EDGES 800000
#define HIDDEN  256
#define OUT_DIM 10
#define LN_EPS  1e-5f

#define NP    8                    // node partitions
#define PART  6250                 // nodes per partition
#define ES    32                   // edge slices
#define EPSE  (N_EDGES / ES)       // 25000 edges per slice
#define EPSE4 (EPSE / 4)           // 6250 int4 per slice
#define NH2   (N_NODES / 2)        // 25000 node pairs
#define NPB   64                   // nodes per ln block
#define LNB   ((N_NODES + NPB - 1) / NPB)   // 782 blocks

// ---------------- D1: histogram + ticket-fused dinv/y ----------------------
// Block (slice s, part p): LDS hist over its edge slice; packed u16-pair
// partial store. Last-of-32 block per partition reduces -> dinv, y.
__global__ __launch_bounds__(1024) void hist_dinvy_kernel(
    const int4* __restrict__ dst4, const float4* __restrict__ nf4,
    unsigned* __restrict__ degp32, float2* __restrict__ dinv2,
    float4* __restrict__ y4, unsigned* __restrict__ ticketA,
    const float4* __restrict__ Wh4, const float4* __restrict__ Wo4)
{
    __shared__ unsigned hist[PART];          // 25 KB
    __shared__ unsigned oldv;
    const int tid = threadIdx.x;
    const int s = blockIdx.x, p = blockIdx.y;
    const int gb = p * ES + s;

    // L3-warm MLP weights for D3's tail (keep-alive, no DCE)
    if (gb < 17) {
        const int idx = gb * 1024 + tid;
        if (idx < 16384) {
            const float4 v = Wh4[idx];
            asm volatile("" :: "v"(v.x + v.y + v.z + v.w));
        } else if (idx < 17024) {
            const float4 v = Wo4[idx - 16384];
            asm volatile("" :: "v"(v.x + v.y + v.z + v.w));
        }
    }

    for (int i = tid; i < PART; i += 1024) hist[i] = 0u;
    __syncthreads();

    const int base = p * PART;
    const int b0 = s * EPSE4;
    for (int i = tid; i < EPSE4; i += 1024) {
        const int4 d = dst4[b0 + i];
        unsigned r;
        r = (unsigned)(d.x - base); if (r < PART) atomicAdd(&hist[r], 1u);
        r = (unsigned)(d.y - base); if (r < PART) atomicAdd(&hist[r], 1u);
        r = (unsigned)(d.z - base); if (r < PART) atomicAdd(&hist[r], 1u);
        r = (unsigned)(d.w - base); if (r < PART) atomicAdd(&hist[r], 1u);
    }
    __syncthreads();

    unsigned* outp = degp32 + (size_t)s * NH2 + base / 2;
    for (int i = tid; i < PART / 2; i += 1024)
        outp[i] = (hist[2 * i] & 0xFFFFu) | (hist[2 * i + 1] << 16);
    __syncthreads();

    if (tid == 0)
        oldv = __hip_atomic_fetch_add(&ticketA[p * 16], 1u, __ATOMIC_ACQ_REL,
                                      __HIP_MEMORY_SCOPE_AGENT);
    __syncthreads();
    if (oldv != ES - 1) return;

    // tail: reduce 32 slice partials for this partition -> dinv, y
    for (int i = tid; i < PART / 2; i += 1024) {
        const int idx = base / 2 + i;           // pair index
        unsigned s0 = 0, s1 = 0;
        #pragma unroll
        for (int ss = 0; ss < ES; ++ss) {
            const unsigned d = degp32[(size_t)ss * NH2 + idx];
            s0 += d & 0xFFFFu;
            s1 += d >> 16;
        }
        const float di0 = rsqrtf((float)s0 + 1.0f);
        const float di1 = rsqrtf((float)s1 + 1.0f);
        dinv2[idx] = make_float2(di0, di1);
        const float4 x = nf4[idx];
        y4[idx] = make_float4(di0 * x.x, di0 * x.y, di1 * x.z, di1 * x.w);
    }
}

// ---------------- D2: scatter + ticket-fused dense-T reduce ----------------
// Plain Tpart stores (no global atomics); src4 loaded only when >=1 of 4
// dsts hit this partition (~41%). Last-of-32 per partition sums slices ->
// dense T with plain stores.
__global__ __launch_bounds__(1024) void scatter_kernel(
    const int4* __restrict__ src4, const int4* __restrict__ dst4,
    const float2* __restrict__ y, float2* __restrict__ Tpart2,
    float2* __restrict__ T2, unsigned* __restrict__ ticketB)
{
    __shared__ float Tl[2 * PART];           // 50 KB
    __shared__ unsigned oldv;
    const int tid = threadIdx.x;
    const int s = blockIdx.x, p = blockIdx.y;

    for (int i = tid; i < 2 * PART; i += 1024) Tl[i] = 0.f;
    __syncthreads();

    const int base = p * PART;
    const int b0 = s * EPSE4;
    for (int i = tid; i < EPSE4; i += 1024) {
        const int4 d = dst4[b0 + i];
        const unsigned r0 = (unsigned)(d.x - base);
        const unsigned r1 = (unsigned)(d.y - base);
        const unsigned r2 = (unsigned)(d.z - base);
        const unsigned r3 = (unsigned)(d.w - base);
        if ((r0 < PART) | (r1 < PART) | (r2 < PART) | (r3 < PART)) {
            const int4 sv = src4[b0 + i];
            if (r0 < PART) { const float2 ys = y[sv.x]; atomicAdd(&Tl[2*r0], ys.x); atomicAdd(&Tl[2*r0+1], ys.y); }
            if (r1 < PART) { const float2 ys = y[sv.y]; atomicAdd(&Tl[2*r1], ys.x); atomicAdd(&Tl[2*r1+1], ys.y); }
            if (r2 < PART) { const float2 ys = y[sv.z]; atomicAdd(&Tl[2*r2], ys.x); atomicAdd(&Tl[2*r2+1], ys.y); }
            if (r3 < PART) { const float2 ys = y[sv.w]; atomicAdd(&Tl[2*r3], ys.x); atomicAdd(&Tl[2*r3+1], ys.y); }
        }
    }
    __syncthreads();

    {
        float2* outp = Tpart2 + (size_t)s * N_NODES + base;
        const float2* Tl2 = (const float2*)Tl;
        for (int i = tid; i < PART; i += 1024) outp[i] = Tl2[i];
    }
    __syncthreads();

    if (tid == 0)
        oldv = __hip_atomic_fetch_add(&ticketB[p * 16], 1u, __ATOMIC_ACQ_REL,
                                      __HIP_MEMORY_SCOPE_AGENT);
    __syncthreads();
    if (oldv != ES - 1) return;

    // tail: dense T for this partition (plain stores, ~1.6 MB coalesced read)
    for (int i = tid; i < PART; i += 1024) {
        float ax = 0.f, ay = 0.f;
        #pragma unroll
        for (int ss = 0; ss < ES; ++ss) {
            const float2 v = Tpart2[(size_t)ss * N_NODES + base + i];
            ax += v.x; ay += v.y;
        }
        T2[base + i] = make_float2(ax, ay);
    }
}

// ---- D3: dense-T LN (scalar-load pass1) + 8-way atomic pool + MLP tail ----
__global__ __launch_bounds__(256) void ln_pool_mlp_kernel(
    const float2* __restrict__ T2,
    const float2* __restrict__ y,
    const float* __restrict__ dinv,
    const float* __restrict__ Wg, const float* __restrict__ bg,
    const float* __restrict__ gamma, const float* __restrict__ beta,
    const float* __restrict__ Wh, const float* __restrict__ bh,
    const float* __restrict__ Wo, const float* __restrict__ bo,
    float* __restrict__ pooled8,
    unsigned* __restrict__ ticket,
    float* __restrict__ out)
{
    const int tid  = threadIdx.x;
    const int bid  = blockIdx.x;
    const int n0   = bid * NPB;
    const int lane = tid & 63;
    const int wv   = tid >> 6;               // 4 waves == 4 j-groups

    __shared__ float4 nd[NPB];               // (s0, s1, r, r*mu)
    __shared__ float  ps[4][NPB];
    __shared__ float  qs[4][NPB];
    __shared__ float  red[4][HIDDEN];
    __shared__ float  pz[HIDDEN], zz[HIDDEN];
    __shared__ float  lgp[OUT_DIM][16], lg[OUT_DIM];
    __shared__ int    is_last;

    if (tid < NPB) {
        const int n = n0 + tid;
        float s0 = 0.f, s1 = 0.f;
        if (n < N_NODES) {
            const float di = dinv[n];
            const float2 yn = y[n];
            const float2 t  = T2[n];
            s0 = di * (t.x + yn.x);
            s1 = di * (t.y + yn.y);
        }
        nd[tid] = make_float4(s0, s1, 0.f, 0.f);
    }
    __syncthreads();

    // pass 1: lane = node, wave = 64-col group; W via wave-uniform scalar loads
    {
        const int jgu = __builtin_amdgcn_readfirstlane(wv);
        const float* w0p = Wg + jgu * 64;
        const float* w1p = Wg + HIDDEN + jgu * 64;
        const float* bgp = bg + jgu * 64;
        const float4 d = nd[lane];
        float sumA = 0.f, sumB = 0.f, sqA = 0.f, sqB = 0.f;
        #pragma unroll 8
        for (int j = 0; j < 64; j += 2) {
            const float va = fmaxf(fmaf(d.y, w1p[j],     fmaf(d.x, w0p[j],     bgp[j])),     0.f);
            const float vb = fmaxf(fmaf(d.y, w1p[j + 1], fmaf(d.x, w0p[j + 1], bgp[j + 1])), 0.f);
            sumA += va; sqA = fmaf(va, va, sqA);
            sumB += vb; sqB = fmaf(vb, vb, sqB);
        }
        ps[wv][lane] = sumA + sumB;
        qs[wv][lane] = sqA + sqB;
    }
    __syncthreads();

    if (tid < NPB) {
        const float sum = ps[0][tid] + ps[1][tid] + ps[2][tid] + ps[3][tid];
        const float sq  = qs[0][tid] + qs[1][tid] + qs[2][tid] + qs[3][tid];
        const float mu  = sum * (1.0f / HIDDEN);
        const float var = sq * (1.0f / HIDDEN) - mu * mu;
        float r = rsqrtf(var + LN_EPS);
        if (n0 + tid >= N_NODES) r = 0.f;
        const float4 d = nd[tid];
        nd[tid] = make_float4(d.x, d.y, r, r * mu);
    }
    __syncthreads();

    // pass 2: wave = 16 nodes, lane = 4 columns
    {
        const float4 w0  = *reinterpret_cast<const float4*>(&Wg[lane * 4]);
        const float4 w1  = *reinterpret_cast<const float4*>(&Wg[HIDDEN + lane * 4]);
        const float4 bgv = *reinterpret_cast<const float4*>(&bg[lane * 4]);

        float a0 = 0.f, a1 = 0.f, a2 = 0.f, a3 = 0.f;
        #pragma unroll
        for (int k = 0; k < 16; ++k) {
            const float4 d = nd[wv * 16 + k];    // broadcast read
            const float v0 = fmaxf(fmaf(d.y, w1.x, fmaf(d.x, w0.x, bgv.x)), 0.f);
            const float v1 = fmaxf(fmaf(d.y, w1.y, fmaf(d.x, w0.y, bgv.y)), 0.f);
            const float v2 = fmaxf(fmaf(d.y, w1.z, fmaf(d.x, w0.z, bgv.z)), 0.f);
            const float v3 = fmaxf(fmaf(d.y, w1.w, fmaf(d.x, w0.w, bgv.w)), 0.f);
            a0 += fmaf(d.z, v0, -d.w);
            a1 += fmaf(d.z, v1, -d.w);
            a2 += fmaf(d.z, v2, -d.w);
            a3 += fmaf(d.z, v3, -d.w);
        }
        red[wv][lane * 4 + 0] = a0;
        red[wv][lane * 4 + 1] = a1;
        red[wv][lane * 4 + 2] = a2;
        red[wv][lane * 4 + 3] = a3;
    }
    __syncthreads();

    atomicAdd(&pooled8[(bid & 7) * HIDDEN + tid],
              red[0][tid] + red[1][tid] + red[2][tid] + red[3][tid]);
    __syncthreads();

    if (tid == 0) {
        const unsigned old = __hip_atomic_fetch_add(ticket, 1u, __ATOMIC_ACQ_REL,
                                                    __HIP_MEMORY_SCOPE_AGENT);
        is_last = (old == (unsigned)(gridDim.x - 1));
    }
    __syncthreads();
    if (!is_last) return;

    {
        float S = 0.f;
        #pragma unroll
        for (int k = 0; k < 8; ++k) S += pooled8[k * HIDDEN + tid];
        pz[tid] = gamma[tid] * S + (float)N_NODES * beta[tid];
    }
    __syncthreads();

    {
        float acc = bh[tid];
        #pragma unroll 8
        for (int k = 0; k < HIDDEN; ++k) acc = fmaf(pz[k], Wh[k * HIDDEN + tid], acc);
        zz[tid] = fmaxf(acc, 0.f);
    }
    __syncthreads();

    if (tid < OUT_DIM * 16) {
        const int o = tid >> 4, kc = tid & 15;
        float acc = 0.f;
        #pragma unroll
        for (int k = kc * 16; k < kc * 16 + 16; ++k)
            acc = fmaf(zz[k], Wo[k * OUT_DIM + o], acc);
        lgp[o][kc] = acc;
    }
    __syncthreads();
    if (tid < OUT_DIM) {
        float t = bo[tid];
        #pragma unroll
        for (int q = 0; q < 16; ++q) t += lgp[tid][q];
        lg[tid] = t;
    }
    __syncthreads();

    if (tid == 0) {
        float m = lg[0];
        for (int k = 1; k < OUT_DIM; ++k) m = fmaxf(m, lg[k]);
        float sum = 0.f;
        for (int k = 0; k < OUT_DIM; ++k) sum += expf(lg[k] - m);
        const float lse = m + logf(sum);
        for (int k = 0; k < OUT_DIM; ++k) out[k] = lg[k] - lse;
    }
}

// ---------------------------------------------------------------- launch ----
extern "C" void kernel_launch(void* const* d_in, const int* in_sizes, int n_in,
                              void* d_out, int out_size, void* d_ws, size_t ws_size,
                              hipStream_t stream) {
    const float* nf    = (const float*)d_in[0];   // [N, 2]
    const int*   ei    = (const int*)  d_in[1];   // [2, E] int32
    const float* Wg    = (const float*)d_in[2];
    const float* bg    = (const float*)d_in[3];
    const float* gamma = (const float*)d_in[4];
    const float* beta  = (const float*)d_in[5];
    const float* Wh    = (const float*)d_in[6];
    const float* bh    = (const float*)d_in[7];
    const float* Wo    = (const float*)d_in[8];
    const float* bo    = (const float*)d_in[9];
    float* out = (float*)d_out;

    const int* srcp = ei;
    const int* dstp = ei + N_EDGES;               // 3.2MB offset: 16B-aligned

    // workspace layout (4B units):
    // ticketA [NP*16] | ticketB [NP*16] | mlp_ticket [16] | pooled8 [8*H]
    // | degp32 [ES*NH2] (3.2MB) | Tpart2 [ES*N] float2 (12.8MB)
    // | T [2N] | dinv [N] | y [2N]
    unsigned* ticketA = (unsigned*)d_ws;
    unsigned* ticketB = ticketA + NP * 16;
    unsigned* mlp_ticket = ticketB + NP * 16;
    float* pooled8 = (float*)(mlp_ticket + 16);
    unsigned* degp32 = (unsigned*)(pooled8 + 8 * HIDDEN);
    float* Tpart = (float*)(degp32 + (size_t)ES * NH2);
    float* T     = Tpart + (size_t)ES * 2 * N_NODES;
    float* dinvp = T + 2 * N_NODES;
    float* yp    = dinvp + N_NODES;

    // zero tickets + pooled8 (poison/replay-safe)
    hipMemsetAsync(d_ws, 0, (size_t)(2 * NP * 16 + 16 + 8 * HIDDEN) * 4, stream);

    dim3 pg(ES, NP);
    hist_dinvy_kernel<<<pg, 1024, 0, stream>>>((const int4*)dstp, (const float4*)nf,
                                               degp32, (float2*)dinvp, (float4*)yp,
                                               ticketA, (const float4*)Wh, (const float4*)Wo);
    scatter_kernel<<<pg, 1024, 0, stream>>>((const int4*)srcp, (const int4*)dstp,
                                            (const float2*)yp, (float2*)Tpart,
                                            (float2*)T, ticketB);
    ln_pool_mlp_kernel<<<LNB, 256, 0, stream>>>((const float2*)T, (const float2*)yp, dinvp,
                                                Wg, bg, gamma, beta, Wh, bh, Wo, bo,
                                                pooled8, mlp_ticket, out);
}

// Round 14
// 63.992 us; speedup vs baseline: 1.7297x; 1.7297x over previous
//
#include <hip/hip_runtime.h>
#include <math.h>

#define N_NODES 50000
#define N_EDGES 800000
#define HIDDEN  256
#define OUT_DIM 10
#define LN_EPS  1e-5f

#define NP    8                    // node partitions
#define PART  6250                 // nodes per partition
#define ES    32                   // edge slices
#define EPSE  (N_EDGES / ES)       // 25000 edges per slice
#define EPSE4 (EPSE / 4)           // 6250 int4 per slice
#define NH2   (N_NODES / 2)        // 25000 node pairs
#define NPB   64                   // nodes per ln block
#define LNB   ((N_NODES + NPB - 1) / NPB)   // 782 blocks

// ---------------- D1: privatized histogram (plain partial stores) ----------
// Block (slice s, part p): LDS hist over its edge slice; packed u16-pair
// store. Block (0,0) zeroes pooled8; first 17 blocks L3-warm Wh/Wo.
__global__ __launch_bounds__(1024) void hist_kernel(
    const int4* __restrict__ dst4, unsigned* __restrict__ degp32,
    float* __restrict__ pooled8,
    const float4* __restrict__ Wh4, const float4* __restrict__ Wo4)
{
    __shared__ unsigned hist[PART];          // 25 KB
    const int tid = threadIdx.x;
    const int s = blockIdx.x, p = blockIdx.y;
    const int gb = p * ES + s;

    if (gb == 0) { pooled8[tid] = 0.f; pooled8[tid + 1024] = 0.f; }
    // L3-warm MLP weights for D5's single-block tail (keep-alive, no DCE)
    if (gb < 17) {
        const int idx = gb * 1024 + tid;
        if (idx < 16384) {
            const float4 v = Wh4[idx];
            asm volatile("" :: "v"(v.x + v.y + v.z + v.w));
        } else if (idx < 17024) {
            const float4 v = Wo4[idx - 16384];
            asm volatile("" :: "v"(v.x + v.y + v.z + v.w));
        }
    }

    for (int i = tid; i < PART; i += 1024) hist[i] = 0u;
    __syncthreads();

    const int base = p * PART;
    const int b0 = s * EPSE4;
    for (int i = tid; i < EPSE4; i += 1024) {
        const int4 d = dst4[b0 + i];
        unsigned r;
        r = (unsigned)(d.x - base); if (r < PART) atomicAdd(&hist[r], 1u);
        r = (unsigned)(d.y - base); if (r < PART) atomicAdd(&hist[r], 1u);
        r = (unsigned)(d.z - base); if (r < PART) atomicAdd(&hist[r], 1u);
        r = (unsigned)(d.w - base); if (r < PART) atomicAdd(&hist[r], 1u);
    }
    __syncthreads();

    unsigned* outp = degp32 + (size_t)s * NH2 + base / 2;
    for (int i = tid; i < PART / 2; i += 1024)
        outp[i] = (hist[2 * i] & 0xFFFFu) | (hist[2 * i + 1] << 16);
}

// ---------------- D2: deg reduce -> dinv, y = dinv * x ---------------------
__global__ __launch_bounds__(256) void dinv_y_kernel(
    const unsigned* __restrict__ degp32, const float4* __restrict__ nf4,
    float2* __restrict__ dinv2, float4* __restrict__ y4)
{
    const int t = blockIdx.x * 256 + threadIdx.x;   // pair index
    if (t >= NH2) return;
    unsigned s0 = 0, s1 = 0;
    #pragma unroll
    for (int s = 0; s < ES; ++s) {
        const unsigned d = degp32[(size_t)s * NH2 + t];
        s0 += d & 0xFFFFu;
        s1 += d >> 16;
    }
    const float di0 = rsqrtf((float)s0 + 1.0f);
    const float di1 = rsqrtf((float)s1 + 1.0f);
    dinv2[t] = make_float2(di0, di1);
    const float4 x = nf4[t];
    y4[t] = make_float4(di0 * x.x, di0 * x.y, di1 * x.z, di1 * x.w);
}

// ---------------- D3: privatized scatter (plain Tpart stores) --------------
__global__ __launch_bounds__(1024) void scatterp_kernel(
    const int4* __restrict__ src4, const int4* __restrict__ dst4,
    const float2* __restrict__ y, float2* __restrict__ Tpart2)
{
    __shared__ float Tl[2 * PART];           // 50 KB
    const int tid = threadIdx.x;
    const int s = blockIdx.x, p = blockIdx.y;

    for (int i = tid; i < 2 * PART; i += 1024) Tl[i] = 0.f;
    __syncthreads();

    const int base = p * PART;
    const int b0 = s * EPSE4;
    for (int i = tid; i < EPSE4; i += 1024) {
        const int4 d = dst4[b0 + i];
        const int4 sv = src4[b0 + i];
        unsigned r;
        r = (unsigned)(d.x - base);
        if (r < PART) { const float2 ys = y[sv.x]; atomicAdd(&Tl[2*r], ys.x); atomicAdd(&Tl[2*r+1], ys.y); }
        r = (unsigned)(d.y - base);
        if (r < PART) { const float2 ys = y[sv.y]; atomicAdd(&Tl[2*r], ys.x); atomicAdd(&Tl[2*r+1], ys.y); }
        r = (unsigned)(d.z - base);
        if (r < PART) { const float2 ys = y[sv.z]; atomicAdd(&Tl[2*r], ys.x); atomicAdd(&Tl[2*r+1], ys.y); }
        r = (unsigned)(d.w - base);
        if (r < PART) { const float2 ys = y[sv.w]; atomicAdd(&Tl[2*r], ys.x); atomicAdd(&Tl[2*r+1], ys.y); }
    }
    __syncthreads();

    float2* outp = Tpart2 + (size_t)s * N_NODES + base;
    const float2* Tl2 = (const float2*)Tl;
    for (int i = tid; i < PART; i += 1024) outp[i] = Tl2[i];
}

// ---------------- D4: coalesced S[n] = dinv*(sum Tpart + y) ----------------
// Thread-per-node; consecutive threads read consecutive float2 per slice.
// Also zeroes the MLP ticket for D5 (kernel-boundary visibility).
__global__ __launch_bounds__(256) void reduceS_kernel(
    const float2* __restrict__ Tpart2, const float2* __restrict__ y,
    const float* __restrict__ dinv, float2* __restrict__ S2,
    unsigned* __restrict__ mlp_ticket)
{
    const int n = blockIdx.x * 256 + threadIdx.x;
    if (blockIdx.x == 0 && threadIdx.x == 0) *mlp_ticket = 0u;
    if (n >= N_NODES) return;
    float ax = 0.f, ay = 0.f;
    #pragma unroll
    for (int ss = 0; ss < ES; ++ss) {
        const float2 v = Tpart2[(size_t)ss * N_NODES + n];
        ax += v.x; ay += v.y;
    }
    const float di = dinv[n];
    const float2 yn = y[n];
    S2[n] = make_float2(di * (ax + yn.x), di * (ay + yn.y));
}

// ---- D5: dense-S LN (scalar-load pass1) + 8-way atomic pool + MLP tail ----
__global__ __launch_bounds__(256) void ln_pool_mlp_kernel(
    const float2* __restrict__ S2,
    const float* __restrict__ Wg, const float* __restrict__ bg,
    const float* __restrict__ gamma, const float* __restrict__ beta,
    const float* __restrict__ Wh, const float* __restrict__ bh,
    const float* __restrict__ Wo, const float* __restrict__ bo,
    float* __restrict__ pooled8,
    unsigned* __restrict__ ticket,
    float* __restrict__ out)
{
    const int tid  = threadIdx.x;
    const int bid  = blockIdx.x;
    const int n0   = bid * NPB;
    const int lane = tid & 63;
    const int wv   = tid >> 6;               // 4 waves == 4 j-groups

    __shared__ float4 nd[NPB];               // (s0, s1, r, r*mu)
    __shared__ float  ps[4][NPB];
    __shared__ float  qs[4][NPB];
    __shared__ float  red[4][HIDDEN];
    __shared__ float  pz[HIDDEN], zz[HIDDEN];
    __shared__ float  lgp[OUT_DIM][16], lg[OUT_DIM];
    __shared__ int    is_last;

    if (tid < NPB) {
        const int n = n0 + tid;
        float2 s = make_float2(0.f, 0.f);
        if (n < N_NODES) s = S2[n];
        nd[tid] = make_float4(s.x, s.y, 0.f, 0.f);
    }
    __syncthreads();

    // pass 1: lane = node, wave = 64-col group; W via wave-uniform scalar loads
    {
        const int jgu = __builtin_amdgcn_readfirstlane(wv);
        const float* w0p = Wg + jgu * 64;
        const float* w1p = Wg + HIDDEN + jgu * 64;
        const float* bgp = bg + jgu * 64;
        const float4 d = nd[lane];
        float sumA = 0.f, sumB = 0.f, sqA = 0.f, sqB = 0.f;
        #pragma unroll 8
        for (int j = 0; j < 64; j += 2) {
            const float va = fmaxf(fmaf(d.y, w1p[j],     fmaf(d.x, w0p[j],     bgp[j])),     0.f);
            const float vb = fmaxf(fmaf(d.y, w1p[j + 1], fmaf(d.x, w0p[j + 1], bgp[j + 1])), 0.f);
            sumA += va; sqA = fmaf(va, va, sqA);
            sumB += vb; sqB = fmaf(vb, vb, sqB);
        }
        ps[wv][lane] = sumA + sumB;
        qs[wv][lane] = sqA + sqB;
    }
    __syncthreads();

    if (tid < NPB) {
        const float sum = ps[0][tid] + ps[1][tid] + ps[2][tid] + ps[3][tid];
        const float sq  = qs[0][tid] + qs[1][tid] + qs[2][tid] + qs[3][tid];
        const float mu  = sum * (1.0f / HIDDEN);
        const float var = sq * (1.0f / HIDDEN) - mu * mu;
        float r = rsqrtf(var + LN_EPS);
        if (n0 + tid >= N_NODES) r = 0.f;
        const float4 d = nd[tid];
        nd[tid] = make_float4(d.x, d.y, r, r * mu);
    }
    __syncthreads();

    // pass 2: wave = 16 nodes, lane = 4 columns
    {
        const float4 w0  = *reinterpret_cast<const float4*>(&Wg[lane * 4]);
        const float4 w1  = *reinterpret_cast<const float4*>(&Wg[HIDDEN + lane * 4]);
        const float4 bgv = *reinterpret_cast<const float4*>(&bg[lane * 4]);

        float a0 = 0.f, a1 = 0.f, a2 = 0.f, a3 = 0.f;
        #pragma unroll
        for (int k = 0; k < 16; ++k) {
            const float4 d = nd[wv * 16 + k];    // broadcast read
            const float v0 = fmaxf(fmaf(d.y, w1.x, fmaf(d.x, w0.x, bgv.x)), 0.f);
            const float v1 = fmaxf(fmaf(d.y, w1.y, fmaf(d.x, w0.y, bgv.y)), 0.f);
            const float v2 = fmaxf(fmaf(d.y, w1.z, fmaf(d.x, w0.z, bgv.z)), 0.f);
            const float v3 = fmaxf(fmaf(d.y, w1.w, fmaf(d.x, w0.w, bgv.w)), 0.f);
            a0 += fmaf(d.z, v0, -d.w);
            a1 += fmaf(d.z, v1, -d.w);
            a2 += fmaf(d.z, v2, -d.w);
            a3 += fmaf(d.z, v3, -d.w);
        }
        red[wv][lane * 4 + 0] = a0;
        red[wv][lane * 4 + 1] = a1;
        red[wv][lane * 4 + 2] = a2;
        red[wv][lane * 4 + 3] = a3;
    }
    __syncthreads();

    // pooled via atomics only (nothing bulk-dirty before the ticket)
    atomicAdd(&pooled8[(bid & 7) * HIDDEN + tid],
              red[0][tid] + red[1][tid] + red[2][tid] + red[3][tid]);
    __syncthreads();

    if (tid == 0) {
        const unsigned old = __hip_atomic_fetch_add(ticket, 1u, __ATOMIC_ACQ_REL,
                                                    __HIP_MEMORY_SCOPE_AGENT);
        is_last = (old == (unsigned)(gridDim.x - 1));
    }
    __syncthreads();
    if (!is_last) return;

    {
        float S = 0.f;
        #pragma unroll
        for (int k = 0; k < 8; ++k) S += pooled8[k * HIDDEN + tid];
        pz[tid] = gamma[tid] * S + (float)N_NODES * beta[tid];
    }
    __syncthreads();

    {
        float acc = bh[tid];
        #pragma unroll 8
        for (int k = 0; k < HIDDEN; ++k) acc = fmaf(pz[k], Wh[k * HIDDEN + tid], acc);
        zz[tid] = fmaxf(acc, 0.f);
    }
    __syncthreads();

    if (tid < OUT_DIM * 16) {
        const int o = tid >> 4, kc = tid & 15;
        float acc = 0.f;
        #pragma unroll
        for (int k = kc * 16; k < kc * 16 + 16; ++k)
            acc = fmaf(zz[k], Wo[k * OUT_DIM + o], acc);
        lgp[o][kc] = acc;
    }
    __syncthreads();
    if (tid < OUT_DIM) {
        float t = bo[tid];
        #pragma unroll
        for (int q = 0; q < 16; ++q) t += lgp[tid][q];
        lg[tid] = t;
    }
    __syncthreads();

    if (tid == 0) {
        float m = lg[0];
        for (int k = 1; k < OUT_DIM; ++k) m = fmaxf(m, lg[k]);
        float sum = 0.f;
        for (int k = 0; k < OUT_DIM; ++k) sum += expf(lg[k] - m);
        const float lse = m + logf(sum);
        for (int k = 0; k < OUT_DIM; ++k) out[k] = lg[k] - lse;
    }
}

// ---------------------------------------------------------------- launch ----
extern "C" void kernel_launch(void* const* d_in, const int* in_sizes, int n_in,
                              void* d_out, int out_size, void* d_ws, size_t ws_size,
                              hipStream_t stream) {
    const float* nf    = (const float*)d_in[0];   // [N, 2]
    const int*   ei    = (const int*)  d_in[1];   // [2, E] int32
    const float* Wg    = (const float*)d_in[2];
    const float* bg    = (const float*)d_in[3];
    const float* gamma = (const float*)d_in[4];
    const float* beta  = (const float*)d_in[5];
    const float* Wh    = (const float*)d_in[6];
    const float* bh    = (const float*)d_in[7];
    const float* Wo    = (const float*)d_in[8];
    const float* bo    = (const float*)d_in[9];
    float* out = (float*)d_out;

    const int* srcp = ei;
    const int* dstp = ei + N_EDGES;               // 3.2MB offset: 16B-aligned

    // workspace layout (4B units):
    // pooled8 [8*H] | mlp_ticket [16] | degp32 [ES*NH2] (3.2MB)
    // | Tpart2 [ES*N] float2 (12.8MB) | dinv [N] | y [2N] | S [2N]
    float* pooled8 = (float*)d_ws;
    unsigned* mlp_ticket = (unsigned*)(pooled8 + 8 * HIDDEN);
    unsigned* degp32 = mlp_ticket + 16;
    float* Tpart = (float*)(degp32 + (size_t)ES * NH2);
    float* dinvp = Tpart + (size_t)ES * 2 * N_NODES;
    float* yp    = dinvp + N_NODES;
    float* Sp    = yp + 2 * N_NODES;

    dim3 pg(ES, NP);
    hist_kernel<<<pg, 1024, 0, stream>>>((const int4*)dstp, degp32, pooled8,
                                         (const float4*)Wh, (const float4*)Wo);
    dinv_y_kernel<<<(NH2 + 255) / 256, 256, 0, stream>>>(degp32, (const float4*)nf,
                                                         (float2*)dinvp, (float4*)yp);
    scatterp_kernel<<<pg, 1024, 0, stream>>>((const int4*)srcp, (const int4*)dstp,
                                             (const float2*)yp, (float2*)Tpart);
    reduceS_kernel<<<(N_NODES + 255) / 256, 256, 0, stream>>>((const float2*)Tpart,
                                                              (const float2*)yp, dinvp,
                                                              (float2*)Sp, mlp_ticket);
    ln_pool_mlp_kernel<<<LNB, 256, 0, stream>>>((const float2*)Sp,
                                                Wg, bg, gamma, beta, Wh, bh, Wo, bo,
                                                pooled8, mlp_ticket, out);
}

// Round 15
// 60.268 us; speedup vs baseline: 1.8366x; 1.0618x over previous
//
#include <hip/hip_runtime.h>
#include <math.h>

#define N_NODES 50000
#define N_EDGES 800000
#define HIDDEN  256
#define OUT_DIM 10
#define LN_EPS  1e-5f

#define NP    8                    // node partitions
#define PART  6250                 // nodes per partition
#define ES    32                   // edge slices
#define EPSE  (N_EDGES / ES)       // 25000 edges per slice
#define EPSE4 (EPSE / 4)           // 6250 int4 per slice
#define NH2   (N_NODES / 2)        // 25000 node pairs
#define NPB   64                   // nodes per ln block == chunk size
#define LNB   ((N_NODES + NPB - 1) / NPB)   // 782 blocks / chunks

// ---------------- D1: privatized histogram (plain partial stores) ----------
__global__ __launch_bounds__(1024) void hist_kernel(
    const int4* __restrict__ dst4, unsigned* __restrict__ degp32,
    float* __restrict__ pooled8,
    const float4* __restrict__ Wh4, const float4* __restrict__ Wo4)
{
    __shared__ unsigned hist[PART];          // 25 KB
    const int tid = threadIdx.x;
    const int s = blockIdx.x, p = blockIdx.y;
    const int gb = p * ES + s;

    if (gb == 0) { pooled8[tid] = 0.f; pooled8[tid + 1024] = 0.f; }
    // L3-warm MLP weights for D4's single-block tail (keep-alive, no DCE)
    if (gb < 17) {
        const int idx = gb * 1024 + tid;
        if (idx < 16384) {
            const float4 v = Wh4[idx];
            asm volatile("" :: "v"(v.x + v.y + v.z + v.w));
        } else if (idx < 17024) {
            const float4 v = Wo4[idx - 16384];
            asm volatile("" :: "v"(v.x + v.y + v.z + v.w));
        }
    }

    for (int i = tid; i < PART; i += 1024) hist[i] = 0u;
    __syncthreads();

    const int base = p * PART;
    const int b0 = s * EPSE4;
    for (int i = tid; i < EPSE4; i += 1024) {
        const int4 d = dst4[b0 + i];
        unsigned r;
        r = (unsigned)(d.x - base); if (r < PART) atomicAdd(&hist[r], 1u);
        r = (unsigned)(d.y - base); if (r < PART) atomicAdd(&hist[r], 1u);
        r = (unsigned)(d.z - base); if (r < PART) atomicAdd(&hist[r], 1u);
        r = (unsigned)(d.w - base); if (r < PART) atomicAdd(&hist[r], 1u);
    }
    __syncthreads();

    unsigned* outp = degp32 + (size_t)s * NH2 + base / 2;
    for (int i = tid; i < PART / 2; i += 1024)
        outp[i] = (hist[2 * i] & 0xFFFFu) | (hist[2 * i + 1] << 16);
}

// ---------------- D2: deg reduce -> dinv, y = dinv * x ---------------------
// Also zeroes the MLP ticket (boundary before D4 guarantees visibility).
__global__ __launch_bounds__(256) void dinv_y_kernel(
    const unsigned* __restrict__ degp32, const float4* __restrict__ nf4,
    float2* __restrict__ dinv2, float4* __restrict__ y4,
    unsigned* __restrict__ mlp_ticket)
{
    const int t = blockIdx.x * 256 + threadIdx.x;   // pair index
    if (t == 0) *mlp_ticket = 0u;
    if (t >= NH2) return;
    unsigned s0 = 0, s1 = 0;
    #pragma unroll
    for (int s = 0; s < ES; ++s) {
        const unsigned d = degp32[(size_t)s * NH2 + t];
        s0 += d & 0xFFFFu;
        s1 += d >> 16;
    }
    const float di0 = rsqrtf((float)s0 + 1.0f);
    const float di1 = rsqrtf((float)s1 + 1.0f);
    dinv2[t] = make_float2(di0, di1);
    const float4 x = nf4[t];
    y4[t] = make_float4(di0 * x.x, di0 * x.y, di1 * x.z, di1 * x.w);
}

// ---------------- D3: privatized scatter, chunk-transposed partials --------
// TpartB[chunk][slice][64 nodes]: flush stays coalesced (512B runs), and the
// D4 consumer reads ONE contiguous 16KB block per chunk. src4 loaded only
// when >=1 of 4 dsts hit this partition (~41%).
__global__ __launch_bounds__(1024) void scatterp_kernel(
    const int4* __restrict__ src4, const int4* __restrict__ dst4,
    const float2* __restrict__ y, float2* __restrict__ TpartB2)
{
    __shared__ float Tl[2 * PART];           // 50 KB
    const int tid = threadIdx.x;
    const int s = blockIdx.x, p = blockIdx.y;

    for (int i = tid; i < 2 * PART; i += 1024) Tl[i] = 0.f;
    __syncthreads();

    const int base = p * PART;
    const int b0 = s * EPSE4;
    for (int i = tid; i < EPSE4; i += 1024) {
        const int4 d = dst4[b0 + i];
        const unsigned r0 = (unsigned)(d.x - base);
        const unsigned r1 = (unsigned)(d.y - base);
        const unsigned r2 = (unsigned)(d.z - base);
        const unsigned r3 = (unsigned)(d.w - base);
        if ((r0 < PART) | (r1 < PART) | (r2 < PART) | (r3 < PART)) {
            const int4 sv = src4[b0 + i];
            if (r0 < PART) { const float2 ys = y[sv.x]; atomicAdd(&Tl[2*r0], ys.x); atomicAdd(&Tl[2*r0+1], ys.y); }
            if (r1 < PART) { const float2 ys = y[sv.y]; atomicAdd(&Tl[2*r1], ys.x); atomicAdd(&Tl[2*r1+1], ys.y); }
            if (r2 < PART) { const float2 ys = y[sv.z]; atomicAdd(&Tl[2*r2], ys.x); atomicAdd(&Tl[2*r2+1], ys.y); }
            if (r3 < PART) { const float2 ys = y[sv.w]; atomicAdd(&Tl[2*r3], ys.x); atomicAdd(&Tl[2*r3+1], ys.y); }
        }
    }
    __syncthreads();

    const float2* Tl2 = (const float2*)Tl;
    for (int i = tid; i < PART; i += 1024) {
        const int n = base + i;
        const int idx = (((n >> 6) * ES + s) << 6) | (n & 63);
        TpartB2[idx] = Tl2[i];
    }
}

// ---- D4: chunk reduce + LN (scalar-load pass1) + atomic pool + MLP tail ----
// Block bid == chunk bid: reads its contiguous 16KB of TpartB, reduces the 32
// slices in-block, then LN / pool / ticketed MLP head (ticket-after-atomics
// only -- nothing bulk-dirty).
__global__ __launch_bounds__(256) void ln_pool_mlp_kernel(
    const float2* __restrict__ TpartB2,
    const float2* __restrict__ y,
    const float* __restrict__ dinv,
    const float* __restrict__ Wg, const float* __restrict__ bg,
    const float* __restrict__ gamma, const float* __restrict__ beta,
    const float* __restrict__ Wh, const float* __restrict__ bh,
    const float* __restrict__ Wo, const float* __restrict__ bo,
    float* __restrict__ pooled8,
    unsigned* __restrict__ ticket,
    float* __restrict__ out)
{
    const int tid  = threadIdx.x;
    const int bid  = blockIdx.x;
    const int n0   = bid * NPB;
    const int lane = tid & 63;
    const int wv   = tid >> 6;               // 4 waves

    __shared__ float4 nd[NPB];               // (s0, s1, r, r*mu)
    __shared__ float  ps[4][NPB];
    __shared__ float  qs[4][NPB];
    __shared__ float  red[4][HIDDEN];
    __shared__ float  pz[HIDDEN], zz[HIDDEN];
    __shared__ float  lgp[OUT_DIM][16], lg[OUT_DIM];
    __shared__ int    is_last;

    // chunk-local Tpart reduce: wave w sums slices 8w..8w+7 (contiguous 512B
    // per iteration), LDS-combine the 4 wave partials.
    {
        const float2* tp = TpartB2 + (size_t)bid * (ES * NPB);
        float ax = 0.f, ay = 0.f;
        #pragma unroll
        for (int s8 = 0; s8 < 8; ++s8) {
            const float2 v = tp[((wv << 3) + s8) * NPB + lane];
            ax += v.x; ay += v.y;
        }
        ps[wv][lane] = ax;
        qs[wv][lane] = ay;
    }
    __syncthreads();

    if (tid < NPB) {
        const int n = n0 + tid;
        float s0 = 0.f, s1 = 0.f;
        if (n < N_NODES) {
            const float tx = ps[0][tid] + ps[1][tid] + ps[2][tid] + ps[3][tid];
            const float ty = qs[0][tid] + qs[1][tid] + qs[2][tid] + qs[3][tid];
            const float di = dinv[n];
            const float2 yn = y[n];
            s0 = di * (tx + yn.x);
            s1 = di * (ty + yn.y);
        }
        nd[tid] = make_float4(s0, s1, 0.f, 0.f);
    }
    __syncthreads();

    // pass 1: lane = node, wave = 64-col group; W via wave-uniform scalar loads
    {
        const int jgu = __builtin_amdgcn_readfirstlane(wv);
        const float* w0p = Wg + jgu * 64;
        const float* w1p = Wg + HIDDEN + jgu * 64;
        const float* bgp = bg + jgu * 64;
        const float4 d = nd[lane];
        float sumA = 0.f, sumB = 0.f, sqA = 0.f, sqB = 0.f;
        #pragma unroll 8
        for (int j = 0; j < 64; j += 2) {
            const float va = fmaxf(fmaf(d.y, w1p[j],     fmaf(d.x, w0p[j],     bgp[j])),     0.f);
            const float vb = fmaxf(fmaf(d.y, w1p[j + 1], fmaf(d.x, w0p[j + 1], bgp[j + 1])), 0.f);
            sumA += va; sqA = fmaf(va, va, sqA);
            sumB += vb; sqB = fmaf(vb, vb, sqB);
        }
        ps[wv][lane] = sumA + sumB;
        qs[wv][lane] = sqA + sqB;
    }
    __syncthreads();

    if (tid < NPB) {
        const float sum = ps[0][tid] + ps[1][tid] + ps[2][tid] + ps[3][tid];
        const float sq  = qs[0][tid] + qs[1][tid] + qs[2][tid] + qs[3][tid];
        const float mu  = sum * (1.0f / HIDDEN);
        const float var = sq * (1.0f / HIDDEN) - mu * mu;
        float r = rsqrtf(var + LN_EPS);
        if (n0 + tid >= N_NODES) r = 0.f;
        const float4 d = nd[tid];
        nd[tid] = make_float4(d.x, d.y, r, r * mu);
    }
    __syncthreads();

    // pass 2: wave = 16 nodes, lane = 4 columns
    {
        const float4 w0  = *reinterpret_cast<const float4*>(&Wg[lane * 4]);
        const float4 w1  = *reinterpret_cast<const float4*>(&Wg[HIDDEN + lane * 4]);
        const float4 bgv = *reinterpret_cast<const float4*>(&bg[lane * 4]);

        float a0 = 0.f, a1 = 0.f, a2 = 0.f, a3 = 0.f;
        #pragma unroll
        for (int k = 0; k < 16; ++k) {
            const float4 d = nd[wv * 16 + k];    // broadcast read
            const float v0 = fmaxf(fmaf(d.y, w1.x, fmaf(d.x, w0.x, bgv.x)), 0.f);
            const float v1 = fmaxf(fmaf(d.y, w1.y, fmaf(d.x, w0.y, bgv.y)), 0.f);
            const float v2 = fmaxf(fmaf(d.y, w1.z, fmaf(d.x, w0.z, bgv.z)), 0.f);
            const float v3 = fmaxf(fmaf(d.y, w1.w, fmaf(d.x, w0.w, bgv.w)), 0.f);
            a0 += fmaf(d.z, v0, -d.w);
            a1 += fmaf(d.z, v1, -d.w);
            a2 += fmaf(d.z, v2, -d.w);
            a3 += fmaf(d.z, v3, -d.w);
        }
        red[wv][lane * 4 + 0] = a0;
        red[wv][lane * 4 + 1] = a1;
        red[wv][lane * 4 + 2] = a2;
        red[wv][lane * 4 + 3] = a3;
    }
    __syncthreads();

    // pooled via atomics only (nothing bulk-dirty before the ticket)
    atomicAdd(&pooled8[(bid & 7) * HIDDEN + tid],
              red[0][tid] + red[1][tid] + red[2][tid] + red[3][tid]);
    __syncthreads();

    if (tid == 0) {
        const unsigned old = __hip_atomic_fetch_add(ticket, 1u, __ATOMIC_ACQ_REL,
                                                    __HIP_MEMORY_SCOPE_AGENT);
        is_last = (old == (unsigned)(gridDim.x - 1));
    }
    __syncthreads();
    if (!is_last) return;

    {
        float S = 0.f;
        #pragma unroll
        for (int k = 0; k < 8; ++k) S += pooled8[k * HIDDEN + tid];
        pz[tid] = gamma[tid] * S + (float)N_NODES * beta[tid];
    }
    __syncthreads();

    {
        float acc = bh[tid];
        #pragma unroll 8
        for (int k = 0; k < HIDDEN; ++k) acc = fmaf(pz[k], Wh[k * HIDDEN + tid], acc);
        zz[tid] = fmaxf(acc, 0.f);
    }
    __syncthreads();

    if (tid < OUT_DIM * 16) {
        const int o = tid >> 4, kc = tid & 15;
        float acc = 0.f;
        #pragma unroll
        for (int k = kc * 16; k < kc * 16 + 16; ++k)
            acc = fmaf(zz[k], Wo[k * OUT_DIM + o], acc);
        lgp[o][kc] = acc;
    }
    __syncthreads();
    if (tid < OUT_DIM) {
        float t = bo[tid];
        #pragma unroll
        for (int q = 0; q < 16; ++q) t += lgp[tid][q];
        lg[tid] = t;
    }
    __syncthreads();

    if (tid == 0) {
        float m = lg[0];
        for (int k = 1; k < OUT_DIM; ++k) m = fmaxf(m, lg[k]);
        float sum = 0.f;
        for (int k = 0; k < OUT_DIM; ++k) sum += expf(lg[k] - m);
        const float lse = m + logf(sum);
        for (int k = 0; k < OUT_DIM; ++k) out[k] = lg[k] - lse;
    }
}

// ---------------------------------------------------------------- launch ----
extern "C" void kernel_launch(void* const* d_in, const int* in_sizes, int n_in,
                              void* d_out, int out_size, void* d_ws, size_t ws_size,
                              hipStream_t stream) {
    const float* nf    = (const float*)d_in[0];   // [N, 2]
    const int*   ei    = (const int*)  d_in[1];   // [2, E] int32
    const float* Wg    = (const float*)d_in[2];
    const float* bg    = (const float*)d_in[3];
    const float* gamma = (const float*)d_in[4];
    const float* beta  = (const float*)d_in[5];
    const float* Wh    = (const float*)d_in[6];
    const float* bh    = (const float*)d_in[7];
    const float* Wo    = (const float*)d_in[8];
    const float* bo    = (const float*)d_in[9];
    float* out = (float*)d_out;

    const int* srcp = ei;
    const int* dstp = ei + N_EDGES;               // 3.2MB offset: 16B-aligned

    // workspace layout (4B units):
    // pooled8 [8*H] | mlp_ticket [16] | degp32 [ES*NH2] (3.2MB)
    // | TpartB [LNB*ES*64] float2 (12.8MB) | dinv [N] | y [2N]
    float* pooled8 = (float*)d_ws;
    unsigned* mlp_ticket = (unsigned*)(pooled8 + 8 * HIDDEN);
    unsigned* degp32 = mlp_ticket + 16;
    float* TpartB = (float*)(degp32 + (size_t)ES * NH2);
    float* dinvp  = TpartB + (size_t)LNB * ES * NPB * 2;
    float* yp     = dinvp + N_NODES;

    dim3 pg(ES, NP);
    hist_kernel<<<pg, 1024, 0, stream>>>((const int4*)dstp, degp32, pooled8,
                                         (const float4*)Wh, (const float4*)Wo);
    dinv_y_kernel<<<(NH2 + 255) / 256, 256, 0, stream>>>(degp32, (const float4*)nf,
                                                         (float2*)dinvp, (float4*)yp,
                                                         mlp_ticket);
    scatterp_kernel<<<pg, 1024, 0, stream>>>((const int4*)srcp, (const int4*)dstp,
                                             (const float2*)yp, (float2*)TpartB);
    ln_pool_mlp_kernel<<<LNB, 256, 0, stream>>>((const float2*)TpartB,
                                                (const float2*)yp, dinvp,
                                                Wg, bg, gamma, beta, Wh, bh, Wo, bo,
                                                pooled8, mlp_ticket, out);
}

// Round 16
// 51.278 us; speedup vs baseline: 2.1586x; 1.1753x over previous
//
#include <hip/hip_runtime.h>
#include <math.h>

#define N_NODES 50000
#define N_EDGES 800000
#define HIDDEN  256
#define OUT_DIM 10
#define LN_EPS  1e-5f

#define NP    8                    // node partitions
#define PART  6250                 // nodes per partition
#define ES    32                   // edge slices
#define EPSE  (N_EDGES / ES)       // 25000 edges per slice
#define EPSE4 (EPSE / 4)           // 6250 int4 per slice
#define NH2   (N_NODES / 2)        // 25000 node pairs
#define NPB   128                  // nodes per ln block == chunk size
#define LNB   ((N_NODES + NPB - 1) / NPB)   // 391 blocks / chunks

// ---------------- D1: privatized histogram (plain partial stores) ----------
__global__ __launch_bounds__(1024) void hist_kernel(
    const int4* __restrict__ dst4, unsigned* __restrict__ degp32,
    float* __restrict__ pooled8,
    const float4* __restrict__ Wh4, const float4* __restrict__ Wo4)
{
    __shared__ unsigned hist[PART];          // 25 KB
    const int tid = threadIdx.x;
    const int s = blockIdx.x, p = blockIdx.y;
    const int gb = p * ES + s;

    if (gb == 0) { pooled8[tid] = 0.f; pooled8[tid + 1024] = 0.f; }
    // L3-warm MLP weights for D4's single-block tail (keep-alive, no DCE)
    if (gb < 17) {
        const int idx = gb * 1024 + tid;
        if (idx < 16384) {
            const float4 v = Wh4[idx];
            asm volatile("" :: "v"(v.x + v.y + v.z + v.w));
        } else if (idx < 17024) {
            const float4 v = Wo4[idx - 16384];
            asm volatile("" :: "v"(v.x + v.y + v.z + v.w));
        }
    }

    for (int i = tid; i < PART; i += 1024) hist[i] = 0u;
    __syncthreads();

    const int base = p * PART;
    const int b0 = s * EPSE4;
    for (int i = tid; i < EPSE4; i += 1024) {
        const int4 d = dst4[b0 + i];
        unsigned r;
        r = (unsigned)(d.x - base); if (r < PART) atomicAdd(&hist[r], 1u);
        r = (unsigned)(d.y - base); if (r < PART) atomicAdd(&hist[r], 1u);
        r = (unsigned)(d.z - base); if (r < PART) atomicAdd(&hist[r], 1u);
        r = (unsigned)(d.w - base); if (r < PART) atomicAdd(&hist[r], 1u);
    }
    __syncthreads();

    unsigned* outp = degp32 + (size_t)s * NH2 + base / 2;
    for (int i = tid; i < PART / 2; i += 1024)
        outp[i] = (hist[2 * i] & 0xFFFFu) | (hist[2 * i + 1] << 16);
}

// ---------------- D2: deg reduce -> dinv, y = dinv * x ---------------------
// Also zeroes the MLP ticket (boundary before D4 guarantees visibility).
__global__ __launch_bounds__(256) void dinv_y_kernel(
    const unsigned* __restrict__ degp32, const float4* __restrict__ nf4,
    float2* __restrict__ dinv2, float4* __restrict__ y4,
    unsigned* __restrict__ mlp_ticket)
{
    const int t = blockIdx.x * 256 + threadIdx.x;   // pair index
    if (t == 0) *mlp_ticket = 0u;
    if (t >= NH2) return;
    unsigned s0 = 0, s1 = 0;
    #pragma unroll
    for (int s = 0; s < ES; ++s) {
        const unsigned d = degp32[(size_t)s * NH2 + t];
        s0 += d & 0xFFFFu;
        s1 += d >> 16;
    }
    const float di0 = rsqrtf((float)s0 + 1.0f);
    const float di1 = rsqrtf((float)s1 + 1.0f);
    dinv2[t] = make_float2(di0, di1);
    const float4 x = nf4[t];
    y4[t] = make_float4(di0 * x.x, di0 * x.y, di1 * x.z, di1 * x.w);
}

// ---------------- D3: privatized scatter, chunk-transposed partials --------
// TpartB[chunk][slice][128 nodes]: flush coalesced (1KB runs, split only at
// partition edges), D4 reads ONE contiguous 32KB block per chunk.
__global__ __launch_bounds__(1024) void scatterp_kernel(
    const int4* __restrict__ src4, const int4* __restrict__ dst4,
    const float2* __restrict__ y, float2* __restrict__ TpartB2)
{
    __shared__ float Tl[2 * PART];           // 50 KB
    const int tid = threadIdx.x;
    const int s = blockIdx.x, p = blockIdx.y;

    for (int i = tid; i < 2 * PART; i += 1024) Tl[i] = 0.f;
    __syncthreads();

    const int base = p * PART;
    const int b0 = s * EPSE4;
    for (int i = tid; i < EPSE4; i += 1024) {
        const int4 d = dst4[b0 + i];
        const unsigned r0 = (unsigned)(d.x - base);
        const unsigned r1 = (unsigned)(d.y - base);
        const unsigned r2 = (unsigned)(d.z - base);
        const unsigned r3 = (unsigned)(d.w - base);
        if ((r0 < PART) | (r1 < PART) | (r2 < PART) | (r3 < PART)) {
            const int4 sv = src4[b0 + i];
            if (r0 < PART) { const float2 ys = y[sv.x]; atomicAdd(&Tl[2*r0], ys.x); atomicAdd(&Tl[2*r0+1], ys.y); }
            if (r1 < PART) { const float2 ys = y[sv.y]; atomicAdd(&Tl[2*r1], ys.x); atomicAdd(&Tl[2*r1+1], ys.y); }
            if (r2 < PART) { const float2 ys = y[sv.z]; atomicAdd(&Tl[2*r2], ys.x); atomicAdd(&Tl[2*r2+1], ys.y); }
            if (r3 < PART) { const float2 ys = y[sv.w]; atomicAdd(&Tl[2*r3], ys.x); atomicAdd(&Tl[2*r3+1], ys.y); }
        }
    }
    __syncthreads();

    const float2* Tl2 = (const float2*)Tl;
    for (int i = tid; i < PART; i += 1024) {
        const int n = base + i;
        const int idx = (((n >> 7) * ES + s) << 7) | (n & 127);
        TpartB2[idx] = Tl2[i];
    }
}

// ---- D4: chunk reduce + LN + pool + ticketed MLP tail (512 threads) -------
// Block bid == chunk bid (128 nodes). 8 waves: chunk reduce 4 slices/wave;
// pass1 = 4 col-groups x 2 node-halves (no cross-lane ops); pass2 = 8 waves
// x 16 nodes. Ticket-after-atomics only.
__global__ __launch_bounds__(512) void ln_pool_mlp_kernel(
    const float2* __restrict__ TpartB2,
    const float2* __restrict__ y,
    const float* __restrict__ dinv,
    const float* __restrict__ Wg, const float* __restrict__ bg,
    const float* __restrict__ gamma, const float* __restrict__ beta,
    const float* __restrict__ Wh, const float* __restrict__ bh,
    const float* __restrict__ Wo, const float* __restrict__ bo,
    float* __restrict__ pooled8,
    unsigned* __restrict__ ticket,
    float* __restrict__ out)
{
    const int tid  = threadIdx.x;
    const int bid  = blockIdx.x;
    const int n0   = bid * NPB;
    const int lane = tid & 63;
    const int wv   = tid >> 6;               // 8 waves

    __shared__ float4 nd[NPB];               // 2 KB (s0, s1, r, r*mu)
    __shared__ float  psx[8][NPB];           // 4 KB
    __shared__ float  psy[8][NPB];           // 4 KB
    __shared__ float  red[8][HIDDEN];        // 8 KB
    __shared__ float  pz[HIDDEN], zz[HIDDEN];
    __shared__ float  lgp[OUT_DIM][16], lg[OUT_DIM];
    __shared__ int    is_last;

    // chunk-local Tpart reduce: wave w sums slices 4w..4w+3 for both
    // node-halves (contiguous 1KB rows).
    {
        const float2* tp = TpartB2 + (size_t)bid * (ES * NPB);
        float ax0 = 0.f, ay0 = 0.f, ax1 = 0.f, ay1 = 0.f;
        #pragma unroll
        for (int s4 = 0; s4 < 4; ++s4) {
            const int row = ((wv << 2) + s4) << 7;
            const float2 v0 = tp[row + lane];
            const float2 v1 = tp[row + 64 + lane];
            ax0 += v0.x; ay0 += v0.y;
            ax1 += v1.x; ay1 += v1.y;
        }
        psx[wv][lane] = ax0;      psy[wv][lane] = ay0;
        psx[wv][64 + lane] = ax1; psy[wv][64 + lane] = ay1;
    }
    __syncthreads();

    if (tid < NPB) {
        const int n = n0 + tid;
        float s0 = 0.f, s1 = 0.f;
        if (n < N_NODES) {
            float tx = 0.f, ty = 0.f;
            #pragma unroll
            for (int w = 0; w < 8; ++w) { tx += psx[w][tid]; ty += psy[w][tid]; }
            const float di = dinv[n];
            const float2 yn = y[n];
            s0 = di * (tx + yn.x);
            s1 = di * (ty + yn.y);
        }
        nd[tid] = make_float4(s0, s1, 0.f, 0.f);
    }
    __syncthreads();

    // pass 1: wave = (node-half h, col-group jg); lane = node within half.
    // W via wave-uniform scalar loads; no cross-lane ops.
    {
        const int wu  = __builtin_amdgcn_readfirstlane(wv);
        const int h   = wu & 1;
        const int jg  = wu >> 1;
        const float* w0p = Wg + jg * 64;
        const float* w1p = Wg + HIDDEN + jg * 64;
        const float* bgp = bg + jg * 64;
        const int node = h * 64 + lane;
        const float4 d = nd[node];
        float sumA = 0.f, sumB = 0.f, sqA = 0.f, sqB = 0.f;
        #pragma unroll 8
        for (int j = 0; j < 64; j += 2) {
            const float va = fmaxf(fmaf(d.y, w1p[j],     fmaf(d.x, w0p[j],     bgp[j])),     0.f);
            const float vb = fmaxf(fmaf(d.y, w1p[j + 1], fmaf(d.x, w0p[j + 1], bgp[j + 1])), 0.f);
            sumA += va; sqA = fmaf(va, va, sqA);
            sumB += vb; sqB = fmaf(vb, vb, sqB);
        }
        psx[jg][node] = sumA + sumB;   // reuse psx/psy as [4][128] sums
        psy[jg][node] = sqA + sqB;
    }
    __syncthreads();

    if (tid < NPB) {
        const float sum = psx[0][tid] + psx[1][tid] + psx[2][tid] + psx[3][tid];
        const float sq  = psy[0][tid] + psy[1][tid] + psy[2][tid] + psy[3][tid];
        const float mu  = sum * (1.0f / HIDDEN);
        const float var = sq * (1.0f / HIDDEN) - mu * mu;
        float r = rsqrtf(var + LN_EPS);
        if (n0 + tid >= N_NODES) r = 0.f;
        const float4 d = nd[tid];
        nd[tid] = make_float4(d.x, d.y, r, r * mu);
    }
    __syncthreads();

    // pass 2: wave = 16 nodes, lane = 4 columns
    {
        const float4 w0  = *reinterpret_cast<const float4*>(&Wg[lane * 4]);
        const float4 w1  = *reinterpret_cast<const float4*>(&Wg[HIDDEN + lane * 4]);
        const float4 bgv = *reinterpret_cast<const float4*>(&bg[lane * 4]);

        float a0 = 0.f, a1 = 0.f, a2 = 0.f, a3 = 0.f;
        #pragma unroll
        for (int k = 0; k < 16; ++k) {
            const float4 d = nd[wv * 16 + k];    // broadcast read
            const float v0 = fmaxf(fmaf(d.y, w1.x, fmaf(d.x, w0.x, bgv.x)), 0.f);
            const float v1 = fmaxf(fmaf(d.y, w1.y, fmaf(d.x, w0.y, bgv.y)), 0.f);
            const float v2 = fmaxf(fmaf(d.y, w1.z, fmaf(d.x, w0.z, bgv.z)), 0.f);
            const float v3 = fmaxf(fmaf(d.y, w1.w, fmaf(d.x, w0.w, bgv.w)), 0.f);
            a0 += fmaf(d.z, v0, -d.w);
            a1 += fmaf(d.z, v1, -d.w);
            a2 += fmaf(d.z, v2, -d.w);
            a3 += fmaf(d.z, v3, -d.w);
        }
        red[wv][lane * 4 + 0] = a0;
        red[wv][lane * 4 + 1] = a1;
        red[wv][lane * 4 + 2] = a2;
        red[wv][lane * 4 + 3] = a3;
    }
    __syncthreads();

    // pooled via atomics only (nothing bulk-dirty before the ticket)
    if (tid < HIDDEN) {
        float s = 0.f;
        #pragma unroll
        for (int w = 0; w < 8; ++w) s += red[w][tid];
        atomicAdd(&pooled8[(bid & 7) * HIDDEN + tid], s);
    }
    __syncthreads();

    if (tid == 0) {
        const unsigned old = __hip_atomic_fetch_add(ticket, 1u, __ATOMIC_ACQ_REL,
                                                    __HIP_MEMORY_SCOPE_AGENT);
        is_last = (old == (unsigned)(gridDim.x - 1));
    }
    __syncthreads();
    if (!is_last) return;

    if (tid < HIDDEN) {
        float S = 0.f;
        #pragma unroll
        for (int k = 0; k < 8; ++k) S += pooled8[k * HIDDEN + tid];
        pz[tid] = gamma[tid] * S + (float)N_NODES * beta[tid];
    }
    __syncthreads();

    // z = relu(bh + pooled @ Wh): 2-way k-split over 512 threads
    {
        const int g = tid >> 8;      // 0..1
        const int j = tid & 255;
        float acc = 0.f;
        #pragma unroll 8
        for (int k = g * 128; k < g * 128 + 128; ++k)
            acc = fmaf(pz[k], Wh[k * HIDDEN + j], acc);
        red[g][j] = acc;
    }
    __syncthreads();
    if (tid < HIDDEN)
        zz[tid] = fmaxf(bh[tid] + red[0][tid] + red[1][tid], 0.f);
    __syncthreads();

    // logits: 16 threads per output, 16 k's each
    if (tid < OUT_DIM * 16) {
        const int o = tid >> 4, kc = tid & 15;
        float acc = 0.f;
        #pragma unroll
        for (int k = kc * 16; k < kc * 16 + 16; ++k)
            acc = fmaf(zz[k], Wo[k * OUT_DIM + o], acc);
        lgp[o][kc] = acc;
    }
    __syncthreads();
    if (tid < OUT_DIM) {
        float t = bo[tid];
        #pragma unroll
        for (int q = 0; q < 16; ++q) t += lgp[tid][q];
        lg[tid] = t;
    }
    __syncthreads();

    if (tid == 0) {
        float m = lg[0];
        for (int k = 1; k < OUT_DIM; ++k) m = fmaxf(m, lg[k]);
        float sum = 0.f;
        for (int k = 0; k < OUT_DIM; ++k) sum += expf(lg[k] - m);
        const float lse = m + logf(sum);
        for (int k = 0; k < OUT_DIM; ++k) out[k] = lg[k] - lse;
    }
}

// ---------------------------------------------------------------- launch ----
extern "C" void kernel_launch(void* const* d_in, const int* in_sizes, int n_in,
                              void* d_out, int out_size, void* d_ws, size_t ws_size,
                              hipStream_t stream) {
    const float* nf    = (const float*)d_in[0];   // [N, 2]
    const int*   ei    = (const int*)  d_in[1];   // [2, E] int32
    const float* Wg    = (const float*)d_in[2];
    const float* bg    = (const float*)d_in[3];
    const float* gamma = (const float*)d_in[4];
    const float* beta  = (const float*)d_in[5];
    const float* Wh    = (const float*)d_in[6];
    const float* bh    = (const float*)d_in[7];
    const float* Wo    = (const float*)d_in[8];
    const float* bo    = (const float*)d_in[9];
    float* out = (float*)d_out;

    const int* srcp = ei;
    const int* dstp = ei + N_EDGES;               // 3.2MB offset: 16B-aligned

    // workspace layout (4B units):
    // pooled8 [8*H] | mlp_ticket [16] | degp32 [ES*NH2] (3.2MB)
    // | TpartB [LNB*ES*128] float2 (12.8MB) | dinv [N] | y [2N]
    float* pooled8 = (float*)d_ws;
    unsigned* mlp_ticket = (unsigned*)(pooled8 + 8 * HIDDEN);
    unsigned* degp32 = mlp_ticket + 16;
    float* TpartB = (float*)(degp32 + (size_t)ES * NH2);
    float* dinvp  = TpartB + (size_t)LNB * ES * NPB * 2;
    float* yp     = dinvp + N_NODES;

    dim3 pg(ES, NP);
    hist_kernel<<<pg, 1024, 0, stream>>>((const int4*)dstp, degp32, pooled8,
                                         (const float4*)Wh, (const float4*)Wo);
    dinv_y_kernel<<<(NH2 + 255) / 256, 256, 0, stream>>>(degp32, (const float4*)nf,
                                                         (float2*)dinvp, (float4*)yp,
                                                         mlp_ticket);
    scatterp_kernel<<<pg, 1024, 0, stream>>>((const int4*)srcp, (const int4*)dstp,
                                             (const float2*)yp, (float2*)TpartB);
    ln_pool_mlp_kernel<<<LNB, 512, 0, stream>>>((const float2*)TpartB,
                                                (const float2*)yp, dinvp,
                                                Wg, bg, gamma, beta, Wh, bh, Wo, bo,
                                                pooled8, mlp_ticket, out);
}